// Round 1
// baseline (1788.884 us; speedup 1.0000x reference)
//
#include <hip/hip_runtime.h>
#include <hip/hip_bf16.h>

#define NE 100000
#define NR 500
#define DD 128
#define NT 250000
#define RELOFF 12800000        // NE*DD
#define TWO_NF 500000.0f
#define NTF 250000.0f

__device__ __forceinline__ float bf2f(unsigned short u){
  unsigned int x = ((unsigned int)u) << 16;
  return __uint_as_float(x);
}
__device__ __forceinline__ void atomAddF(float* p, float v){ unsafeAtomicAdd(p, v); }

// ---------------- K1: entity / relation counts ----------------
__global__ void k_count(const int* __restrict__ trip, int* __restrict__ cnt, int* __restrict__ cntR){
  int i = blockIdx.x*blockDim.x + threadIdx.x;
  if (i < NT){
    atomicAdd(&cnt[trip[3*i+0]], 1);
    atomicAdd(&cnt[trip[3*i+1]], 1);
    atomicAdd(&cntR[trip[3*i+2]], 1);
  }
}

// ---------------- K2: count-weighted entity column stats ----------------
__global__ void k_entstats(const float* __restrict__ ent, const int* __restrict__ cnt,
                           float* __restrict__ S, float* __restrict__ Q){
  int j = threadIdx.x;            // 0..127 (column)
  int r0 = blockIdx.x*256;
  int r1 = min(r0+256, NE);
  float s = 0.f, q = 0.f;
  for (int r = r0; r < r1; ++r){
    int w = cnt[r];
    if (w){
      float x = ent[(size_t)r*DD + j];
      float wf = (float)w;
      s += wf*x; q += wf*x*x;
    }
  }
  atomAddF(&S[j], s); atomAddF(&Q[j], q);
}

// ---------------- K3: BN0 fold (alpha/beta) + rel variance.  1 block x 128 ----------------
__global__ void k_alpha(const float* __restrict__ rel, const int* __restrict__ cntR,
                        const float* __restrict__ S, const float* __restrict__ Q,
                        const float* __restrict__ bn0g, const float* __restrict__ bn0b,
                        float* __restrict__ alpha0, float* __restrict__ alpha1, float* __restrict__ alpha2,
                        float* __restrict__ beta0, float* __restrict__ beta1){
  int j = threadIdx.x;
  float qr = 0.f;
  for (int k = 0; k < NR; ++k){
    float w = (float)cntR[k];
    float x = rel[k*DD + j];
    qr += w*x*x;
  }
  float mean = S[j] / TWO_NF;
  float var  = Q[j] / TWO_NF - mean*mean;
  float inv  = rsqrtf(var + 1e-5f);
  float a0 = inv * bn0g[j];
  float a1 = inv * bn0g[128+j];
  alpha0[j] = a0; alpha1[j] = a1;
  beta0[j] = bn0b[j]     - mean*a0;
  beta1[j] = bn0b[128+j] - mean*a1;
  float varR = qr / NTF;                 // rel-column mean is exactly 0
  alpha2[j] = rsqrtf(varR + 1e-5f) * bn0g[256+j];
}

// ---------------- K4: folded bias vector.  128 blocks x 128 ----------------
__global__ void k_bias(const float* __restrict__ aw, const float* __restrict__ ab,
                       const float* __restrict__ bn0b,
                       const float* __restrict__ beta0, const float* __restrict__ beta1,
                       float* __restrict__ bias){
  int o = blockIdx.x, j = threadIdx.x;
  const float* r = aw + (size_t)o*384;
  float p = r[j]*beta0[j] + r[128+j]*beta1[j] + r[256+j]*bn0b[256+j];
  __shared__ float sm[128];
  sm[j] = p; __syncthreads();
  for (int s = 64; s > 0; s >>= 1){ if (j < s) sm[j] += sm[j+s]; __syncthreads(); }
  if (j == 0) bias[o] = ab[o] + sm[0];
}

// ---------------- K5: V table (per-relation transform).  500 blocks x 128 ----------------
__global__ void k_v(const float* __restrict__ rel, const float* __restrict__ aw,
                    const float* __restrict__ alpha2, float* __restrict__ V){
  int k = blockIdx.x, o = threadIdx.x;
  __shared__ float rl[128];
  rl[o] = rel[k*DD + o] * alpha2[o];
  __syncthreads();
  float acc = 0.f;
  #pragma unroll 8
  for (int j = 0; j < 128; ++j) acc += aw[(size_t)o*384 + 256 + j] * rl[j];
  V[k*DD + o] = acc;
}

// ---------------- K6: U table  U[e] = [W0'*ent[e] | W1'*ent[e]]  (bf16) ----------------
__global__ __launch_bounds__(256) void k_u(const float* __restrict__ ent, const float* __restrict__ aw,
                   const float* __restrict__ alpha0, const float* __restrict__ alpha1,
                   __hip_bfloat16* __restrict__ U){
  __shared__ float xs[32*128];
  int tid = threadIdx.x;
  const float* base;
  const float* al;
  if (tid < 128){ base = aw + (size_t)tid*384;             al = alpha0; }
  else          { base = aw + (size_t)(tid-128)*384 + 128; al = alpha1; }
  float w[128];
  #pragma unroll
  for (int j = 0; j < 128; ++j) w[j] = base[j]*al[j];
  int e0 = blockIdx.x*32;                                  // 3125*32 == 100000 exactly
  for (int idx = tid; idx < 32*128; idx += 256) xs[idx] = ent[(size_t)e0*DD + idx];
  __syncthreads();
  for (int r = 0; r < 32; ++r){
    const float4* x4 = (const float4*)&xs[r*DD];
    float acc = 0.f;
    #pragma unroll
    for (int j = 0; j < 32; ++j){
      float4 x = x4[j];
      acc += x.x*w[4*j] + x.y*w[4*j+1] + x.z*w[4*j+2] + x.w*w[4*j+3];
    }
    U[(size_t)(e0+r)*256 + tid] = __float2bfloat16(acc);
  }
}

// ---------------- K7: BN1 column stats (stream triplets; wave = one triplet) ----------------
__global__ __launch_bounds__(256) void k_c1(const int* __restrict__ trip,
                   const __hip_bfloat16* __restrict__ U, const float* __restrict__ V,
                   const float* __restrict__ bias,
                   float* __restrict__ colsum, float* __restrict__ colsumsq){
  int lane = threadIdx.x & 63;
  int wv = blockIdx.x*(blockDim.x>>6) + (threadIdx.x>>6);
  int nw = gridDim.x*(blockDim.x>>6);
  int c0 = 2*lane, c1 = 2*lane+1;
  float b0 = bias[c0], b1 = bias[c1];
  const ushort2* Ub = (const ushort2*)U;          // U row = 128 ushort2
  const float2*  Vp = (const float2*)V;
  float s0=0.f, s1=0.f, q0=0.f, q1=0.f;
  for (int i = wv; i < NT; i += nw){
    int t0 = trip[3*i+0], t1 = trip[3*i+1], t2 = trip[3*i+2];
    ushort2 a0 = Ub[(size_t)t0*128 + lane];       // U0[t0] cols c0,c1
    ushort2 a1 = Ub[(size_t)t0*128 + 64 + lane];  // U1[t0]
    ushort2 d0 = Ub[(size_t)t1*128 + lane];       // U0[t1]
    ushort2 d1 = Ub[(size_t)t1*128 + 64 + lane];  // U1[t1]
    float2  v  = Vp[(size_t)t2*64 + lane];
    float h00=bf2f(a0.x), h01=bf2f(a0.y), h10=bf2f(a1.x), h11=bf2f(a1.y);
    float t00=bf2f(d0.x), t01=bf2f(d0.y), t10=bf2f(d1.x), t11=bf2f(d1.y);
    float yf0 = h00 + t10 + v.x + b0;
    float yf1 = h01 + t11 + v.y + b1;
    float yb0 = t00 + h10 - v.x + b0;
    float yb1 = t01 + h11 - v.y + b1;
    s0 += yf0 + yb0;  s1 += yf1 + yb1;
    q0 += yf0*yf0 + yb0*yb0;  q1 += yf1*yf1 + yb1*yb1;
  }
  atomAddF(&colsum[c0], s0);   atomAddF(&colsum[c1], s1);
  atomAddF(&colsumsq[c0], q0); atomAddF(&colsumsq[c1], q1);
}

// ---------------- K8: BN1 fold + a2 fold.  1 block x 128 ----------------
__global__ void k_bn1fin(const float* __restrict__ colsum, const float* __restrict__ colsumsq,
                         const float* __restrict__ bn1g, const float* __restrict__ bn1b,
                         const float* __restrict__ a2w, const float* __restrict__ a2b,
                         float* __restrict__ A1, float* __restrict__ B1,
                         float* __restrict__ a2A, float* __restrict__ sbase){
  int j = threadIdx.x;
  float mean = colsum[j] / TWO_NF;
  float var  = colsumsq[j] / TWO_NF - mean*mean;
  float A = rsqrtf(var + 1e-5f) * bn1g[j];
  float B = bn1b[j] - mean*A;
  A1[j] = A; B1[j] = B;
  float w2 = a2w[j];
  a2A[j] = w2*A;
  __shared__ float sm[128];
  sm[j] = w2*B; __syncthreads();
  for (int s = 64; s > 0; s >>= 1){ if (j < s) sm[j] += sm[j+s]; __syncthreads(); }
  if (j == 0) sbase[0] = a2b[0] + sm[0];
}

// ---------------- K9: main output pass (recompute y, BN1, dot, exp, scatter) ----------------
__global__ __launch_bounds__(256) void k_c2(const int* __restrict__ trip,
                   const __hip_bfloat16* __restrict__ U, const float* __restrict__ V,
                   const float* __restrict__ bias,
                   const float* __restrict__ A1, const float* __restrict__ B1,
                   const float* __restrict__ a2A, const float* __restrict__ sbase,
                   float* __restrict__ out, float* __restrict__ ebs){
  int lane = threadIdx.x & 63;
  int wv = blockIdx.x*(blockDim.x>>6) + (threadIdx.x>>6);
  int nw = gridDim.x*(blockDim.x>>6);
  int c0 = 2*lane, c1 = 2*lane+1;
  float b0  = bias[c0], b1  = bias[c1];
  float A10 = A1[c0],  A11 = A1[c1];
  float B10 = B1[c0],  B11 = B1[c1];
  float w20 = a2A[c0], w21 = a2A[c1];
  float sb  = sbase[0];
  const ushort2* Ub = (const ushort2*)U;
  const float2*  Vp = (const float2*)V;
  for (int i = wv; i < NT; i += nw){
    int t0 = trip[3*i+0], t1 = trip[3*i+1], t2 = trip[3*i+2];
    ushort2 a0 = Ub[(size_t)t0*128 + lane];
    ushort2 a1 = Ub[(size_t)t0*128 + 64 + lane];
    ushort2 d0 = Ub[(size_t)t1*128 + lane];
    ushort2 d1 = Ub[(size_t)t1*128 + 64 + lane];
    float2  v  = Vp[(size_t)t2*64 + lane];
    float h00=bf2f(a0.x), h01=bf2f(a0.y), h10=bf2f(a1.x), h11=bf2f(a1.y);
    float t00=bf2f(d0.x), t01=bf2f(d0.y), t10=bf2f(d1.x), t11=bf2f(d1.y);
    float yf0 = h00 + t10 + v.x + b0;
    float yf1 = h01 + t11 + v.y + b1;
    float yb0 = t00 + h10 - v.x + b0;
    float yb1 = t01 + h11 - v.y + b1;
    float pf = yf0*w20 + yf1*w21;
    float pb = yb0*w20 + yb1*w21;
    #pragma unroll
    for (int off = 32; off > 0; off >>= 1){
      pf += __shfl_xor(pf, off, 64);
      pb += __shfl_xor(pb, off, 64);
    }
    float sf = pf + sb, sw = pb + sb;
    float bF = (sf >= 0.f) ? -sf : -0.01f*sf;
    float bB = (sw >= 0.f) ? -sw : -0.01f*sw;
    float eF = expf(bF);
    float eB = expf(bB);
    float cf0 = yf0*A10 + B10, cf1 = yf1*A11 + B11;
    float cb0 = yb0*A10 + B10, cb1 = yb1*A11 + B11;
    float tf0 = eF*cf0, tf1 = eF*cf1;
    float tb0 = eB*cb0, tb1 = eB*cb1;
    atomAddF(&out[(size_t)t0*DD + c0], tf0);
    atomAddF(&out[(size_t)t0*DD + c1], tf1);
    atomAddF(&out[(size_t)t1*DD + c0], tb0);
    atomAddF(&out[(size_t)t1*DD + c1], tb1);
    atomAddF(&out[(size_t)RELOFF + (size_t)t2*DD + c0], tf0);
    atomAddF(&out[(size_t)RELOFF + (size_t)t2*DD + c1], tf1);
    if (lane == 0){
      atomAddF(&ebs[t0], eF);
      atomAddF(&ebs[t1], eB);
    }
  }
}

// ---------------- K10/K11: finalize divisions ----------------
__global__ void k_fin_ent(float* __restrict__ out, const float* __restrict__ ebs){
  int idx = blockIdx.x*blockDim.x + threadIdx.x;   // NE*DD threads exactly
  int e = idx >> 7;
  float d = ebs[e];
  d = (d == 0.f) ? 1e-12f : d;
  out[idx] = out[idx] / d;
}
__global__ void k_fin_rel(float* __restrict__ out, const int* __restrict__ cntR){
  int idx = blockIdx.x*blockDim.x + threadIdx.x;   // NR*DD threads exactly
  int k = idx >> 7;
  float c = fmaxf((float)cntR[k], 1.f);
  out[RELOFF + idx] = out[RELOFF + idx] / c;
}

extern "C" void kernel_launch(void* const* d_in, const int* in_sizes, int n_in,
                              void* d_out, int out_size, void* d_ws, size_t ws_size,
                              hipStream_t stream) {
  (void)in_sizes; (void)n_in; (void)ws_size;
  const int*   trip = (const int*)  d_in[0];
  const float* ent  = (const float*)d_in[1];
  const float* rel  = (const float*)d_in[2];
  const float* aw   = (const float*)d_in[3];
  const float* ab   = (const float*)d_in[4];
  const float* a2w  = (const float*)d_in[5];
  const float* a2b  = (const float*)d_in[6];
  const float* bn0g = (const float*)d_in[7];
  const float* bn0b = (const float*)d_in[8];
  const float* bn1g = (const float*)d_in[9];
  const float* bn1b = (const float*)d_in[10];
  float* out = (float*)d_out;

  char* w = (char*)d_ws;
  size_t off = 0;
  auto take = [&](size_t bytes) -> char* {
    char* p = w + off;
    off = (off + bytes + 511) & ~(size_t)511;
    return p;
  };
  // zeroed region (accumulators)
  float* S        = (float*)take(512);
  float* Q        = (float*)take(512);
  float* colsum   = (float*)take(512);
  float* colsumsq = (float*)take(512);
  float* ebs      = (float*)take((size_t)NE*4);
  int*   cnt      = (int*)  take((size_t)NE*4);
  int*   cntR     = (int*)  take((size_t)NR*4);
  size_t zero_end = off;
  // non-zeroed (fully overwritten each launch)
  float* alpha0 = (float*)take(512);
  float* alpha1 = (float*)take(512);
  float* alpha2 = (float*)take(512);
  float* beta0  = (float*)take(512);
  float* beta1  = (float*)take(512);
  float* biasv  = (float*)take(512);
  float* A1     = (float*)take(512);
  float* B1     = (float*)take(512);
  float* a2A    = (float*)take(512);
  float* sbase  = (float*)take(512);
  float* V      = (float*)take((size_t)NR*DD*4);
  __hip_bfloat16* U = (__hip_bfloat16*)take((size_t)NE*256*2);

  hipMemsetAsync(d_out, 0, (size_t)out_size*sizeof(float), stream);
  hipMemsetAsync(d_ws, 0, zero_end, stream);

  k_count   <<<(NT+255)/256, 256, 0, stream>>>(trip, cnt, cntR);
  k_entstats<<<(NE+255)/256, 128, 0, stream>>>(ent, cnt, S, Q);
  k_alpha   <<<1, 128, 0, stream>>>(rel, cntR, S, Q, bn0g, bn0b, alpha0, alpha1, alpha2, beta0, beta1);
  k_bias    <<<128, 128, 0, stream>>>(aw, ab, bn0b, beta0, beta1, biasv);
  k_v       <<<NR, 128, 0, stream>>>(rel, aw, alpha2, V);
  k_u       <<<NE/32, 256, 0, stream>>>(ent, aw, alpha0, alpha1, U);
  k_c1      <<<2048, 256, 0, stream>>>(trip, U, V, biasv, colsum, colsumsq);
  k_bn1fin  <<<1, 128, 0, stream>>>(colsum, colsumsq, bn1g, bn1b, a2w, a2b, A1, B1, a2A, sbase);
  k_c2      <<<2048, 256, 0, stream>>>(trip, U, V, biasv, A1, B1, a2A, sbase, out, ebs);
  k_fin_ent <<<(NE*DD)/256, 256, 0, stream>>>(out, ebs);
  k_fin_rel <<<(NR*DD)/256, 256, 0, stream>>>(out, cntR);
}

// Round 2
// 1128.388 us; speedup vs baseline: 1.5853x; 1.5853x over previous
//
#include <hip/hip_runtime.h>
#include <hip/hip_bf16.h>

#define NE 100000
#define NR 500
#define DD 128
#define NT 250000
#define RELOFF 12800000        // NE*DD
#define TWO_NF 500000.0f
#define NTF 250000.0f

__device__ __forceinline__ float bf2f(unsigned short u){
  unsigned int x = ((unsigned int)u) << 16;
  return __uint_as_float(x);
}
__device__ __forceinline__ unsigned short f2bf(float f){
  __hip_bfloat16 h = __float2bfloat16(f);
  return *reinterpret_cast<unsigned short*>(&h);
}
__device__ __forceinline__ void atomAddF(float* p, float v){ unsafeAtomicAdd(p, v); }

// ---------------- K1: entity / relation counts ----------------
__global__ void k_count(const int* __restrict__ trip, int* __restrict__ cnt, int* __restrict__ cntR){
  int i = blockIdx.x*blockDim.x + threadIdx.x;
  if (i < NT){
    atomicAdd(&cnt[trip[3*i+0]], 1);
    atomicAdd(&cnt[trip[3*i+1]], 1);
    atomicAdd(&cntR[trip[3*i+2]], 1);
  }
}

// ---------------- scan: entity offsets (exclusive) ----------------
__global__ __launch_bounds__(1024) void k_scan_ent(const int* __restrict__ cnt,
                                                   int* __restrict__ off, int* __restrict__ cur){
  __shared__ int sm[1024];
  __shared__ int carry;
  int t = threadIdx.x;
  if (t == 0) carry = 0;
  __syncthreads();
  for (int base = 0; base < NE; base += 1024){
    int v = (base + t < NE) ? cnt[base + t] : 0;
    sm[t] = v; __syncthreads();
    for (int s = 1; s < 1024; s <<= 1){
      int x = (t >= s) ? sm[t - s] : 0;
      __syncthreads();
      sm[t] += x;
      __syncthreads();
    }
    int incl = sm[t];
    int c = carry;
    __syncthreads();
    if (base + t < NE){
      int ex = c + incl - v;
      off[base + t] = ex;
      cur[base + t] = ex;
    }
    if (t == 1023) carry = c + incl;
    __syncthreads();
  }
  if (t == 0) off[NE] = carry;
}

// ---------------- scan: relation offsets ----------------
__global__ __launch_bounds__(512) void k_scan_rel(const int* __restrict__ cntR,
                                                  int* __restrict__ offR, int* __restrict__ curR){
  __shared__ int sm[512];
  int t = threadIdx.x;
  int v = (t < NR) ? cntR[t] : 0;
  sm[t] = v; __syncthreads();
  for (int s = 1; s < 512; s <<= 1){
    int x = (t >= s) ? sm[t - s] : 0;
    __syncthreads();
    sm[t] += x; __syncthreads();
  }
  if (t < NR){ int ex = sm[t] - v; offR[t] = ex; curR[t] = ex; }
  if (t == 0) offR[NR] = sm[NR-1];
}

// ---------------- scatter events into CSR ----------------
// ent event: other<<10 | rel<<1 | bwdflag   (bwd => -V)
__global__ void k_scatter(const int* __restrict__ trip, int* __restrict__ curE, int* __restrict__ curR,
                          unsigned int* __restrict__ evE, uint2* __restrict__ evR){
  int i = blockIdx.x*blockDim.x + threadIdx.x;
  if (i < NT){
    int t0 = trip[3*i+0], t1 = trip[3*i+1], t2 = trip[3*i+2];
    int p0 = atomicAdd(&curE[t0], 1);
    evE[p0] = ((unsigned)t1 << 10) | ((unsigned)t2 << 1);
    int p1 = atomicAdd(&curE[t1], 1);
    evE[p1] = ((unsigned)t0 << 10) | ((unsigned)t2 << 1) | 1u;
    int p2 = atomicAdd(&curR[t2], 1);
    evR[p2] = make_uint2((unsigned)t0, (unsigned)t1);
  }
}

// ---------------- K2: count-weighted entity column stats ----------------
__global__ __launch_bounds__(256) void k_entstats(const float* __restrict__ ent, const int* __restrict__ cnt,
                                                  float* __restrict__ S, float* __restrict__ Q){
  int j = threadIdx.x & 127;
  int half = threadIdx.x >> 7;
  int r0 = blockIdx.x*128 + half;
  int r1 = min(blockIdx.x*128 + 128, NE);
  float s = 0.f, q = 0.f;
  for (int r = r0; r < r1; r += 2){
    int w = cnt[r];
    if (w){
      float x = ent[(size_t)r*DD + j];
      float wf = (float)w;
      s += wf*x; q += wf*x*x;
    }
  }
  __shared__ float ss[256], qq[256];
  ss[threadIdx.x] = s; qq[threadIdx.x] = q; __syncthreads();
  if (half == 0){
    atomAddF(&S[j], ss[j] + ss[j+128]);
    atomAddF(&Q[j], qq[j] + qq[j+128]);
  }
}

// ---------------- K3: BN0 fold + rel variance ----------------
__global__ void k_alpha(const float* __restrict__ rel, const int* __restrict__ cntR,
                        const float* __restrict__ S, const float* __restrict__ Q,
                        const float* __restrict__ bn0g, const float* __restrict__ bn0b,
                        float* __restrict__ alpha0, float* __restrict__ alpha1, float* __restrict__ alpha2,
                        float* __restrict__ beta0, float* __restrict__ beta1){
  int j = threadIdx.x;
  float qr = 0.f;
  for (int k = 0; k < NR; ++k){
    float w = (float)cntR[k];
    float x = rel[k*DD + j];
    qr += w*x*x;
  }
  float mean = S[j] / TWO_NF;
  float var  = Q[j] / TWO_NF - mean*mean;
  float inv  = rsqrtf(var + 1e-5f);
  float a0 = inv * bn0g[j];
  float a1 = inv * bn0g[128+j];
  alpha0[j] = a0; alpha1[j] = a1;
  beta0[j] = bn0b[j]     - mean*a0;
  beta1[j] = bn0b[128+j] - mean*a1;
  float varR = qr / NTF;
  alpha2[j] = rsqrtf(varR + 1e-5f) * bn0g[256+j];
}

// ---------------- K4: folded bias vector ----------------
__global__ void k_bias(const float* __restrict__ aw, const float* __restrict__ ab,
                       const float* __restrict__ bn0b,
                       const float* __restrict__ beta0, const float* __restrict__ beta1,
                       float* __restrict__ bias){
  int o = blockIdx.x, j = threadIdx.x;
  const float* r = aw + (size_t)o*384;
  float p = r[j]*beta0[j] + r[128+j]*beta1[j] + r[256+j]*bn0b[256+j];
  __shared__ float sm[128];
  sm[j] = p; __syncthreads();
  for (int s = 64; s > 0; s >>= 1){ if (j < s) sm[j] += sm[j+s]; __syncthreads(); }
  if (j == 0) bias[o] = ab[o] + sm[0];
}

// ---------------- K5: V table ----------------
__global__ void k_v(const float* __restrict__ rel, const float* __restrict__ aw,
                    const float* __restrict__ alpha2, float* __restrict__ V){
  int k = blockIdx.x, o = threadIdx.x;
  __shared__ float rl[128];
  rl[o] = rel[k*DD + o] * alpha2[o];
  __syncthreads();
  float acc = 0.f;
  #pragma unroll 8
  for (int j = 0; j < 128; ++j) acc += aw[(size_t)o*384 + 256 + j] * rl[j];
  V[k*DD + o] = acc;
}

// ---------------- K5b: fold W' into transposed bf16 table Wt[k][o] ----------------
__global__ void k_wfold(const float* __restrict__ aw, const float* __restrict__ alpha0,
                        const float* __restrict__ alpha1, unsigned short* __restrict__ Wt){
  int k = blockIdx.x;        // 0..127
  int o = threadIdx.x;       // 0..255
  float w;
  if (o < 128) w = aw[(size_t)o*384 + k] * alpha0[k];
  else         w = aw[(size_t)(o-128)*384 + 128 + k] * alpha1[k];
  Wt[k*256 + o] = f2bf(w);
}

// ---------------- K6: U table via LDS-tiled mini-GEMM ----------------
// block: 32 entities x 256 outputs; thread tile 8 ent x 4 out
__global__ __launch_bounds__(256) void k_u(const float* __restrict__ ent,
                                           const unsigned short* __restrict__ Wt,
                                           unsigned short* __restrict__ Uo){
  __shared__ unsigned short Wl[128*256];   // 64 KB
  __shared__ float xs[32*128];             // 16 KB
  int tid = threadIdx.x;
  {
    const ushort4* src = (const ushort4*)Wt;
    ushort4* dst = (ushort4*)Wl;
    #pragma unroll 4
    for (int i = tid; i < 128*256/4; i += 256) dst[i] = src[i];
  }
  int e0 = blockIdx.x*32;                  // 3125*32 == 100000
  {
    const float4* src = (const float4*)(ent + (size_t)e0*DD);
    float4* dst = (float4*)xs;
    #pragma unroll
    for (int i = tid; i < 32*128/4; i += 256) dst[i] = src[i];
  }
  __syncthreads();
  int to = tid & 63, te = tid >> 6;
  int ob = to*4, ebase = te*8;
  float acc[8][4];
  #pragma unroll
  for (int i = 0; i < 8; ++i){
    #pragma unroll
    for (int j = 0; j < 4; ++j) acc[i][j] = 0.f;
  }
  for (int k = 0; k < 128; ++k){
    ushort4 w4 = *(const ushort4*)&Wl[k*256 + ob];
    float w0 = bf2f(w4.x), w1 = bf2f(w4.y), w2 = bf2f(w4.z), w3 = bf2f(w4.w);
    #pragma unroll
    for (int ei = 0; ei < 8; ++ei){
      float xv = xs[(ebase+ei)*128 + k];   // wave-uniform -> LDS broadcast
      acc[ei][0] += xv*w0; acc[ei][1] += xv*w1;
      acc[ei][2] += xv*w2; acc[ei][3] += xv*w3;
    }
  }
  #pragma unroll
  for (int ei = 0; ei < 8; ++ei){
    ushort4 o4;
    o4.x = f2bf(acc[ei][0]); o4.y = f2bf(acc[ei][1]);
    o4.z = f2bf(acc[ei][2]); o4.w = f2bf(acc[ei][3]);
    *(ushort4*)&Uo[(size_t)(e0 + ebase + ei)*256 + ob] = o4;
  }
}

// ---------------- K7: BN1 column stats ----------------
__global__ __launch_bounds__(256) void k_c1(const int* __restrict__ trip,
                   const __hip_bfloat16* __restrict__ U, const float* __restrict__ V,
                   const float* __restrict__ bias,
                   float* __restrict__ colsum, float* __restrict__ colsumsq){
  int lane = threadIdx.x & 63;
  int wv = blockIdx.x*(blockDim.x>>6) + (threadIdx.x>>6);
  int nw = gridDim.x*(blockDim.x>>6);
  int c0 = 2*lane, c1 = 2*lane+1;
  float b0 = bias[c0], b1 = bias[c1];
  const ushort2* Ub = (const ushort2*)U;
  const float2*  Vp = (const float2*)V;
  float s0=0.f, s1=0.f, q0=0.f, q1=0.f;
  for (int i = wv; i < NT; i += nw){
    int t0 = trip[3*i+0], t1 = trip[3*i+1], t2 = trip[3*i+2];
    ushort2 a0 = Ub[(size_t)t0*128 + lane];
    ushort2 a1 = Ub[(size_t)t0*128 + 64 + lane];
    ushort2 d0 = Ub[(size_t)t1*128 + lane];
    ushort2 d1 = Ub[(size_t)t1*128 + 64 + lane];
    float2  v  = Vp[(size_t)t2*64 + lane];
    float h00=bf2f(a0.x), h01=bf2f(a0.y), h10=bf2f(a1.x), h11=bf2f(a1.y);
    float t00=bf2f(d0.x), t01=bf2f(d0.y), t10=bf2f(d1.x), t11=bf2f(d1.y);
    float yf0 = h00 + t10 + v.x + b0;
    float yf1 = h01 + t11 + v.y + b1;
    float yb0 = t00 + h10 - v.x + b0;
    float yb1 = t01 + h11 - v.y + b1;
    s0 += yf0 + yb0;  s1 += yf1 + yb1;
    q0 += yf0*yf0 + yb0*yb0;  q1 += yf1*yf1 + yb1*yb1;
  }
  atomAddF(&colsum[c0], s0);   atomAddF(&colsum[c1], s1);
  atomAddF(&colsumsq[c0], q0); atomAddF(&colsumsq[c1], q1);
}

// ---------------- K8: BN1 fold + a2 fold ----------------
__global__ void k_bn1fin(const float* __restrict__ colsum, const float* __restrict__ colsumsq,
                         const float* __restrict__ bn1g, const float* __restrict__ bn1b,
                         const float* __restrict__ a2w, const float* __restrict__ a2b,
                         float* __restrict__ A1, float* __restrict__ B1,
                         float* __restrict__ a2A, float* __restrict__ sbase){
  int j = threadIdx.x;
  float mean = colsum[j] / TWO_NF;
  float var  = colsumsq[j] / TWO_NF - mean*mean;
  float A = rsqrtf(var + 1e-5f) * bn1g[j];
  float B = bn1b[j] - mean*A;
  A1[j] = A; B1[j] = B;
  float w2 = a2w[j];
  a2A[j] = w2*A;
  __shared__ float sm[128];
  sm[j] = w2*B; __syncthreads();
  for (int s = 64; s > 0; s >>= 1){ if (j < s) sm[j] += sm[j+s]; __syncthreads(); }
  if (j == 0) sbase[0] = a2b[0] + sm[0];
}

// ---------------- K9: entity gather (one wave per entity) ----------------
__global__ __launch_bounds__(256) void k_gent(const unsigned int* __restrict__ evE, const int* __restrict__ offE,
                   const __hip_bfloat16* __restrict__ U, const float* __restrict__ V,
                   const float* __restrict__ bias,
                   const float* __restrict__ A1, const float* __restrict__ B1,
                   const float* __restrict__ a2A, const float* __restrict__ sbase,
                   float* __restrict__ out){
  int lane = threadIdx.x & 63;
  int e = blockIdx.x*4 + (threadIdx.x>>6);
  if (e >= NE) return;
  int c0 = 2*lane, c1 = c0+1;
  const ushort2* Ub = (const ushort2*)U;
  const float2*  Vp = (const float2*)V;
  ushort2 u0 = Ub[(size_t)e*128 + lane];
  float b0 = bias[c0], b1 = bias[c1];
  float base0 = bf2f(u0.x) + b0, base1 = bf2f(u0.y) + b1;
  float A10 = A1[c0], A11 = A1[c1];
  float B10 = B1[c0], B11 = B1[c1];
  float w20 = a2A[c0], w21 = a2A[c1];
  float sb = sbase[0];
  float hs0 = 0.f, hs1 = 0.f, se = 0.f;
  int p0 = offE[e], p1 = offE[e+1];
  for (int p = p0; p < p1; ++p){
    unsigned ev = evE[p];
    int other = ev >> 10;
    int rl = (ev >> 1) & 0x1FF;
    float sgn = (ev & 1) ? -1.f : 1.f;
    ushort2 u1 = Ub[(size_t)other*128 + 64 + lane];
    float2 v = Vp[rl*64 + lane];
    float y0 = base0 + bf2f(u1.x) + sgn*v.x;
    float y1 = base1 + bf2f(u1.y) + sgn*v.y;
    float pp = y0*w20 + y1*w21;
    #pragma unroll
    for (int o = 32; o > 0; o >>= 1) pp += __shfl_xor(pp, o, 64);
    float s = pp + sb;
    float bb = (s >= 0.f) ? -s : -0.01f*s;
    float eb = expf(bb);
    hs0 += eb*(y0*A10 + B10);
    hs1 += eb*(y1*A11 + B11);
    se  += eb;
  }
  float d = (se == 0.f) ? 1e-12f : se;
  out[(size_t)e*DD + c0] = hs0/d;
  out[(size_t)e*DD + c1] = hs1/d;
}

// ---------------- K10: relation gather (8 blocks x 4 waves per rel) ----------------
__global__ __launch_bounds__(256) void k_grel(const uint2* __restrict__ evR, const int* __restrict__ offR,
                   const __hip_bfloat16* __restrict__ U, const float* __restrict__ V,
                   const float* __restrict__ bias,
                   const float* __restrict__ A1, const float* __restrict__ B1,
                   const float* __restrict__ a2A, const float* __restrict__ sbase,
                   float* __restrict__ out){
  int lane = threadIdx.x & 63;
  int k = blockIdx.x >> 3;
  int sub = (blockIdx.x & 7)*4 + (threadIdx.x >> 6);   // 0..31
  int c0 = 2*lane, c1 = c0+1;
  const ushort2* Ub = (const ushort2*)U;
  const float2*  Vp = (const float2*)V;
  float2 v = Vp[k*64 + lane];
  float b0 = bias[c0], b1 = bias[c1];
  float A10 = A1[c0], A11 = A1[c1];
  float B10 = B1[c0], B11 = B1[c1];
  float w20 = a2A[c0], w21 = a2A[c1];
  float sb = sbase[0];
  float acc0 = 0.f, acc1 = 0.f;
  int p0 = offR[k], p1 = offR[k+1];
  for (int p = p0 + sub; p < p1; p += 32){
    uint2 tt = evR[p];
    ushort2 ua = Ub[(size_t)tt.x*128 + lane];
    ushort2 ud = Ub[(size_t)tt.y*128 + 64 + lane];
    float y0 = bf2f(ua.x) + bf2f(ud.x) + v.x + b0;
    float y1 = bf2f(ua.y) + bf2f(ud.y) + v.y + b1;
    float pp = y0*w20 + y1*w21;
    #pragma unroll
    for (int o = 32; o > 0; o >>= 1) pp += __shfl_xor(pp, o, 64);
    float s = pp + sb;
    float bb = (s >= 0.f) ? -s : -0.01f*s;
    float eb = expf(bb);
    acc0 += eb*(y0*A10 + B10);
    acc1 += eb*(y1*A11 + B11);
  }
  atomAddF(&out[(size_t)RELOFF + (size_t)k*DD + c0], acc0);
  atomAddF(&out[(size_t)RELOFF + (size_t)k*DD + c1], acc1);
}

// ---------------- K11: finalize rel division ----------------
__global__ void k_fin_rel(float* __restrict__ out, const int* __restrict__ cntR){
  int idx = blockIdx.x*blockDim.x + threadIdx.x;   // NR*DD threads
  int k = idx >> 7;
  float c = fmaxf((float)cntR[k], 1.f);
  out[RELOFF + idx] = out[RELOFF + idx] / c;
}

extern "C" void kernel_launch(void* const* d_in, const int* in_sizes, int n_in,
                              void* d_out, int out_size, void* d_ws, size_t ws_size,
                              hipStream_t stream) {
  (void)in_sizes; (void)n_in; (void)ws_size; (void)out_size;
  const int*   trip = (const int*)  d_in[0];
  const float* ent  = (const float*)d_in[1];
  const float* rel  = (const float*)d_in[2];
  const float* aw   = (const float*)d_in[3];
  const float* ab   = (const float*)d_in[4];
  const float* a2w  = (const float*)d_in[5];
  const float* a2b  = (const float*)d_in[6];
  const float* bn0g = (const float*)d_in[7];
  const float* bn0b = (const float*)d_in[8];
  const float* bn1g = (const float*)d_in[9];
  const float* bn1b = (const float*)d_in[10];
  float* out = (float*)d_out;

  char* w = (char*)d_ws;
  size_t off = 0;
  auto take = [&](size_t bytes) -> char* {
    char* p = w + off;
    off = (off + bytes + 511) & ~(size_t)511;
    return p;
  };
  // zeroed region (accumulators)
  float* S        = (float*)take(512);
  float* Q        = (float*)take(512);
  float* colsum   = (float*)take(512);
  float* colsumsq = (float*)take(512);
  int*   cnt      = (int*)  take((size_t)NE*4);
  int*   cntR     = (int*)  take((size_t)NR*4);
  size_t zero_end = off;
  // non-zeroed (fully overwritten each launch)
  float* alpha0 = (float*)take(512);
  float* alpha1 = (float*)take(512);
  float* alpha2 = (float*)take(512);
  float* beta0  = (float*)take(512);
  float* beta1  = (float*)take(512);
  float* biasv  = (float*)take(512);
  float* A1     = (float*)take(512);
  float* B1     = (float*)take(512);
  float* a2A    = (float*)take(512);
  float* sbase  = (float*)take(512);
  int*   offE   = (int*)  take((size_t)(NE+1)*4);
  int*   curE   = (int*)  take((size_t)NE*4);
  int*   offR   = (int*)  take((size_t)(NR+1)*4);
  int*   curR   = (int*)  take((size_t)NR*4);
  unsigned int* evE = (unsigned int*)take((size_t)2*NT*4);
  uint2* evR    = (uint2*)take((size_t)NT*8);
  float* V      = (float*)take((size_t)NR*DD*4);
  unsigned short* Wt = (unsigned short*)take((size_t)128*256*2);
  __hip_bfloat16* U = (__hip_bfloat16*)take((size_t)NE*256*2);

  hipMemsetAsync((char*)d_out + (size_t)RELOFF*4, 0, (size_t)NR*DD*4, stream);
  hipMemsetAsync(d_ws, 0, zero_end, stream);

  k_count    <<<(NT+255)/256, 256, 0, stream>>>(trip, cnt, cntR);
  k_scan_ent <<<1, 1024, 0, stream>>>(cnt, offE, curE);
  k_scan_rel <<<1, 512, 0, stream>>>(cntR, offR, curR);
  k_scatter  <<<(NT+255)/256, 256, 0, stream>>>(trip, curE, curR, evE, evR);
  k_entstats <<<(NE+127)/128, 256, 0, stream>>>(ent, cnt, S, Q);
  k_alpha    <<<1, 128, 0, stream>>>(rel, cntR, S, Q, bn0g, bn0b, alpha0, alpha1, alpha2, beta0, beta1);
  k_bias     <<<128, 128, 0, stream>>>(aw, ab, bn0b, beta0, beta1, biasv);
  k_v        <<<NR, 128, 0, stream>>>(rel, aw, alpha2, V);
  k_wfold    <<<128, 256, 0, stream>>>(aw, alpha0, alpha1, Wt);
  k_u        <<<NE/32, 256, 0, stream>>>(ent, Wt, (unsigned short*)U);
  k_c1       <<<2048, 256, 0, stream>>>(trip, U, V, biasv, colsum, colsumsq);
  k_bn1fin   <<<1, 128, 0, stream>>>(colsum, colsumsq, bn1g, bn1b, a2w, a2b, A1, B1, a2A, sbase);
  k_gent     <<<NE/4, 256, 0, stream>>>(evE, offE, U, V, biasv, A1, B1, a2A, sbase, out);
  k_grel     <<<NR*8, 256, 0, stream>>>(evR, offR, U, V, biasv, A1, B1, a2A, sbase, out);
  k_fin_rel  <<<(NR*DD)/256, 256, 0, stream>>>(out, cntR);
}